// Round 8
// baseline (306.640 us; speedup 1.0000x reference)
//
#include <hip/hip_runtime.h>
#include <hip/hip_bf16.h>
#include <stdint.h>

typedef __attribute__((ext_vector_type(8))) __bf16 bf16x8;
typedef __attribute__((ext_vector_type(16))) float f32x16;
typedef __attribute__((ext_vector_type(4))) unsigned int u32x4;

#define BM 256
#define BN 256
#define BKT 32              // K per ring slot
#define SLOT 16384          // 256 rows x 32 cols x 2B
// ring-5: slots for tiles T..T+4 ; LDS = 5*(16K+16K) = 160 KiB (CU max)

// ---------------- NVFP4 quantize-dequantize (factored: no global scale) ----------------

__device__ __forceinline__ float fp8_e4m3_rne(float x) {
  if (x < 0.015625f) {                       // below min normal 2^-6: subnormal grid 2^-9
    return rintf(x * 512.0f) * 0.001953125f;
  }
  uint32_t u = __float_as_uint(x);
  uint32_t keep = u & 0xFFF00000u;
  uint32_t rem  = u & 0x000FFFFFu;
  uint32_t lsb  = (u >> 20) & 1u;
  if (rem > 0x80000u || (rem == 0x80000u && lsb)) keep += 0x100000u;
  return __uint_as_float(keep);
}

__device__ __forceinline__ float snap_lvl(float a) {
  if (a > 5.0f)  return 6.0f;
  if (a > 3.5f)  return 4.0f;
  if (a > 2.5f)  return 3.0f;
  if (a > 1.75f) return 2.0f;
  if (a > 1.25f) return 1.5f;
  if (a > 0.75f) return 1.0f;
  if (a > 0.25f) return 0.5f;
  return 0.0f;
}

__global__ __launch_bounds__(256) void quant_nvfp4(
    const float* __restrict__ in, unsigned short* __restrict__ out,
    const float* __restrict__ gsp, int nblk) {
  int b = blockIdx.x * 256 + threadIdx.x;
  if (b >= nblk) return;
  float gs = gsp[0];
  const float4* p = reinterpret_cast<const float4*>(in) + (size_t)b * 4;
  float v[16];
#pragma unroll
  for (int i = 0; i < 4; ++i) {
    float4 t4 = p[i];
    v[i * 4 + 0] = t4.x; v[i * 4 + 1] = t4.y;
    v[i * 4 + 2] = t4.z; v[i * 4 + 3] = t4.w;
  }
  float amax = 0.0f;
#pragma unroll
  for (int i = 0; i < 16; ++i) amax = fmaxf(amax, fabsf(v[i]));
  float bs8 = fp8_e4m3_rne(amax / (6.0f * gs));
  float scale = fmaxf(bs8 * gs, 1e-12f);
  unsigned short o[16];
#pragma unroll
  for (int i = 0; i < 16; ++i) {
    float q = v[i] / scale;
    float a = fminf(fabsf(q), 6.0f);
    float val = copysignf(snap_lvl(a) * bs8, q);
    o[i] = (unsigned short)(__float_as_uint(val) >> 16);
  }
  uint4 w0 = make_uint4((uint32_t)o[0] | ((uint32_t)o[1] << 16),
                        (uint32_t)o[2] | ((uint32_t)o[3] << 16),
                        (uint32_t)o[4] | ((uint32_t)o[5] << 16),
                        (uint32_t)o[6] | ((uint32_t)o[7] << 16));
  uint4 w1 = make_uint4((uint32_t)o[8]  | ((uint32_t)o[9]  << 16),
                        (uint32_t)o[10] | ((uint32_t)o[11] << 16),
                        (uint32_t)o[12] | ((uint32_t)o[13] << 16),
                        (uint32_t)o[14] | ((uint32_t)o[15] << 16));
  uint4* op = reinterpret_cast<uint4*>(out + (size_t)b * 16);
  op[0] = w0;
  op[1] = w1;
}

// ---------------- bf16 GEMM, C = A * B^T ; 256x256 tile, ring-5, 32x32x16 MFMA ----------------

__device__ __forceinline__ void async_lds16(const void* g, void* l) {
  __builtin_amdgcn_global_load_lds((__attribute__((address_space(1))) void*)(g),
                                   (__attribute__((address_space(3))) void*)(l),
                                   16, 0, 0);
}

#define DSR(dst, a) asm volatile("ds_read_b128 %0, %1" : "=v"(dst) : "v"(a))
#define LGKM(N) do { asm volatile("s_waitcnt lgkmcnt(" #N ")" ::: "memory"); \
                     __builtin_amdgcn_sched_barrier(0); } while (0)
#define VMC(S) asm volatile("s_waitcnt vmcnt(" S ")" ::: "memory")
#define BCB(x) __builtin_bit_cast(bf16x8, x)

#define MF2(i0, i1, ar, bx, by) do {                                           \
    acc[i0] = __builtin_amdgcn_mfma_f32_32x32x16_bf16(BCB(ar), BCB(bx), acc[i0], 0, 0, 0); \
    acc[i1] = __builtin_amdgcn_mfma_f32_32x32x16_bf16(BCB(ar), BCB(by), acc[i1], 0, 0, 0); \
  } while (0)

#define STAGE_TILE(s, so) {                                                    \
    char* _la = (char*)As + (so);                                              \
    char* _lb = (char*)Bs + (so);                                              \
    async_lds16(pA0 + (size_t)(s) * BKT, _la + lo0);                           \
    async_lds16(pB0 + (size_t)(s) * BKT, _lb + lo0);                           \
    async_lds16(pA1 + (size_t)(s) * BKT, _la + lo1);                           \
    async_lds16(pB1 + (size_t)(s) * BKT, _lb + lo1);                           \
  }

// One K32 tile: single counted vmcnt + single barrier; 12 ds_read_b128 threaded
// through 16 x 32x32x16 MFMA with exact counted lgkm gates.
// RAW: VMC(8) at tile T confirms stage(T) (issued 12 loads back).
// WAR: readers of slot (T+3)%5 drained at LGKM(0) before barrier of tile T-1.
#define TILE(VMSTR, soff, sStg, stgT, DO_S) do {                               \
    u32x4 b00, b10, b01, b11, a0, a1, a2, a3, a4, a5, a6, a7;                  \
    VMC(VMSTR);                                                                \
    __builtin_amdgcn_s_barrier();                                              \
    if (DO_S) { STAGE_TILE(stgT, sStg); }                                      \
    DSR(b00, adB[0] + (soff)); DSR(b10, adB[1] + (soff));                      \
    DSR(b01, adB[2] + (soff)); DSR(b11, adB[3] + (soff));                      \
    DSR(a0, adA[0] + (soff));  DSR(a1, adA[1] + (soff));                       \
    DSR(a2, adA[2] + (soff));  DSR(a3, adA[3] + (soff));                       \
    __builtin_amdgcn_sched_barrier(0);                                         \
    LGKM(3); __builtin_amdgcn_s_setprio(1);                                    \
    MF2(0, 1, a0, b00, b10);                                                   \
    LGKM(2); MF2(2, 3, a1, b00, b10);                                          \
    __builtin_amdgcn_sched_barrier(0);                                         \
    DSR(a4, adA[4] + (soff)); DSR(a5, adA[5] + (soff));                        \
    DSR(a6, adA[6] + (soff)); DSR(a7, adA[7] + (soff));                        \
    __builtin_amdgcn_sched_barrier(0);                                         \
    LGKM(5); MF2(4, 5, a2, b00, b10);                                          \
    LGKM(4); MF2(6, 7, a3, b00, b10);                                          \
    LGKM(3); MF2(0, 1, a4, b01, b11);                                          \
    LGKM(2); MF2(2, 3, a5, b01, b11);                                          \
    LGKM(1); MF2(4, 5, a6, b01, b11);                                          \
    LGKM(0); MF2(6, 7, a7, b01, b11);                                          \
    __builtin_amdgcn_s_setprio(0);                                             \
    __builtin_amdgcn_sched_barrier(0);                                         \
  } while (0)

__global__ __launch_bounds__(512, 2) void gemm_bt_bf16(
    const unsigned short* __restrict__ A, const unsigned short* __restrict__ B,
    const float* __restrict__ bias, const float* __restrict__ gsx,
    const float* __restrict__ gsw, float* __restrict__ C,
    int M, int N, int K) {
  __shared__ __align__(16) unsigned short As[5 * 8192];   // 80 KiB
  __shared__ __align__(16) unsigned short Bs[5 * 8192];   // 80 KiB

  const int t = threadIdx.x;
  const int l = t & 63;
  const int w = t >> 6;
  const int wm = w >> 2, wn = w & 3;     // 2x4 waves; wave tile = 128(M) x 64(N)

  // bijective XCD swizzle (nwg = 512, divisible by 8)
  const int nbn = N / BN;
  const int nwg = (M / BM) * nbn;
  const int cpx = nwg >> 3;
  int bid = blockIdx.x;
  int logical = (bid & 7) * cpx + (bid >> 3);
  const int bm = logical / nbn, bn = logical % nbn;
  const int brow = bm * BM, bcol = bn * BN;

  // staging: linear LDS dest, inverse-swizzled global source (involution q^(((q>>7)&3)<<4))
  unsigned int b0 = (unsigned int)t * 16u;
  unsigned int b1 = b0 + 8192u;
  unsigned int bp0 = b0 ^ (((b0 >> 7) & 3u) << 4);
  unsigned int bp1 = b1 ^ (((b1 >> 7) & 3u) << 4);
  const unsigned int lo0 = b0, lo1 = b1;
  const unsigned short* pA0 = A + (size_t)(brow + (bp0 >> 6)) * K + ((bp0 & 63u) >> 1);
  const unsigned short* pA1 = A + (size_t)(brow + (bp1 >> 6)) * K + ((bp1 & 63u) >> 1);
  const unsigned short* pB0 = B + (size_t)(bcol + (bp0 >> 6)) * K + ((bp0 & 63u) >> 1);
  const unsigned short* pB1 = B + (size_t)(bcol + (bp1 >> 6)) * K + ((bp1 & 63u) >> 1);

  // ---- 32x32x16 fragment read addresses ----
  // A-frag: row = l&31 (m), k = (l>>5)*8 + j ; slot byte = row*64 + (l>>5)*16 + kstep*32
  // B-frag: identical with B rows (n). Swizzle applied on the final byte offset.
  const unsigned baseAu = (unsigned)(uintptr_t)(&As[0]);
  const unsigned baseBu = (unsigned)(uintptr_t)(&Bs[0]);
  unsigned int adA[8], adB[4];
#pragma unroll
  for (int mi = 0; mi < 4; ++mi) {
    unsigned int r = (unsigned)wm * 128u + (unsigned)mi * 32u + ((unsigned)l & 31u);
    unsigned int q0 = r * 64u + (((unsigned)l >> 5) << 4);
    unsigned int q1 = q0 + 32u;
    adA[mi]     = baseAu + (q0 ^ (((q0 >> 7) & 3u) << 4));
    adA[4 + mi] = baseAu + (q1 ^ (((q1 >> 7) & 3u) << 4));
  }
#pragma unroll
  for (int ni = 0; ni < 2; ++ni) {
    unsigned int r = (unsigned)wn * 64u + (unsigned)ni * 32u + ((unsigned)l & 31u);
    unsigned int q0 = r * 64u + (((unsigned)l >> 5) << 4);
    unsigned int q1 = q0 + 32u;
    adB[ni]     = baseBu + (q0 ^ (((q0 >> 7) & 3u) << 4));
    adB[2 + ni] = baseBu + (q1 ^ (((q1 >> 7) & 3u) << 4));
  }

  f32x16 acc[8] = {};   // acc[mi*2+ni] : (wm*128+mi*32) x (wn*64+ni*32)

  // prologue: stage tiles 0,1,2 into slots 0,1,2 (12 loads in flight)
  STAGE_TILE(0, 0);
  STAGE_TILE(1, SLOT);
  STAGE_TILE(2, 2 * SLOT);

  int sa = 0;
#pragma unroll 1
  for (int T = 0; T < 125; ++T) {      // stages tiles 3..127
    int s3 = sa + 3; if (s3 >= 5) s3 -= 5;
    TILE("8", sa * SLOT, s3 * SLOT, T + 3, 1);
    ++sa; if (sa == 5) sa = 0;
  }
  TILE("8", 0 * SLOT, 0, 0, 0);        // tile 125 (slot 0)
  TILE("4", 1 * SLOT, 0, 0, 0);        // tile 126 (slot 1)
  TILE("0", 2 * SLOT, 0, 0, 0);        // tile 127 (slot 2)

  // ---- epilogue (C/D: col=lane&31, row=(reg&3)+8*(reg>>2)+4*(lane>>5); m101) ----
  const float gscale = gsx[0] * gsw[0];
  float bias_r[2];
#pragma unroll
  for (int ni = 0; ni < 2; ++ni)
    bias_r[ni] = bias[bcol + wn * 64 + ni * 32 + (l & 31)];
#pragma unroll
  for (int mi = 0; mi < 4; ++mi) {
#pragma unroll
    for (int ni = 0; ni < 2; ++ni) {
      f32x16 v = acc[mi * 2 + ni];
      int col = bcol + wn * 64 + ni * 32 + (l & 31);
#pragma unroll
      for (int r = 0; r < 16; ++r) {
        int row = brow + wm * 128 + mi * 32 + (r & 3) + 8 * (r >> 2) + 4 * (l >> 5);
        C[(size_t)row * N + col] = v[r] * gscale + bias_r[ni];
      }
    }
  }
}

// ---------------- launch ----------------

extern "C" void kernel_launch(void* const* d_in, const int* in_sizes, int n_in,
                              void* d_out, int out_size, void* d_ws, size_t ws_size,
                              hipStream_t stream) {
  const float* x    = (const float*)d_in[0];
  const float* wgt  = (const float*)d_in[1];
  const float* bias = (const float*)d_in[2];
  const float* isc  = (const float*)d_in[3];
  const float* wsc  = (const float*)d_in[4];
  float* out = (float*)d_out;

  const int N = in_sizes[2];            // 4096
  const int K = in_sizes[1] / N;        // 4096
  const int M = in_sizes[0] / K;        // 8192

  unsigned short* Aq = (unsigned short*)d_ws;
  unsigned short* Bq = Aq + (size_t)M * K;

  int nblkA = M * K / 16;
  quant_nvfp4<<<(nblkA + 255) / 256, 256, 0, stream>>>(x, Aq, isc, nblkA);
  int nblkB = N * K / 16;
  quant_nvfp4<<<(nblkB + 255) / 256, 256, 0, stream>>>(wgt, Bq, wsc, nblkB);

  dim3 grid((M / BM) * (N / BN));
  gemm_bt_bf16<<<grid, 512, 0, stream>>>(Aq, Bq, bias, isc, wsc, out, M, N, K);
}

// Round 9
// 291.747 us; speedup vs baseline: 1.0510x; 1.0510x over previous
//
#include <hip/hip_runtime.h>
#include <hip/hip_bf16.h>
#include <stdint.h>

typedef __attribute__((ext_vector_type(8))) __bf16 bf16x8;
typedef __attribute__((ext_vector_type(4))) float f32x4;
typedef __attribute__((ext_vector_type(4))) unsigned int u32x4;

#define BM 256
#define BN 256
#define BKT 32              // K per ring slot
#define SLOT 16384          // 256 rows x 32 cols x 2B
// ring-4 of K32 slots = 128 KiB LDS (m201's 2-dbuf BK=64 equivalent)

// ---------------- NVFP4 quantize-dequantize (factored: no global scale) ----------------

__device__ __forceinline__ float fp8_e4m3_rne(float x) {
  if (x < 0.015625f) {                       // below min normal 2^-6: subnormal grid 2^-9
    return rintf(x * 512.0f) * 0.001953125f;
  }
  uint32_t u = __float_as_uint(x);
  uint32_t keep = u & 0xFFF00000u;
  uint32_t rem  = u & 0x000FFFFFu;
  uint32_t lsb  = (u >> 20) & 1u;
  if (rem > 0x80000u || (rem == 0x80000u && lsb)) keep += 0x100000u;
  return __uint_as_float(keep);
}

__device__ __forceinline__ float snap_lvl(float a) {
  if (a > 5.0f)  return 6.0f;
  if (a > 3.5f)  return 4.0f;
  if (a > 2.5f)  return 3.0f;
  if (a > 1.75f) return 2.0f;
  if (a > 1.25f) return 1.5f;
  if (a > 0.75f) return 1.0f;
  if (a > 0.25f) return 0.5f;
  return 0.0f;
}

__global__ __launch_bounds__(256) void quant_nvfp4(
    const float* __restrict__ in, unsigned short* __restrict__ out,
    const float* __restrict__ gsp, int nblk) {
  int b = blockIdx.x * 256 + threadIdx.x;
  if (b >= nblk) return;
  float gs = gsp[0];
  const float4* p = reinterpret_cast<const float4*>(in) + (size_t)b * 4;
  float v[16];
#pragma unroll
  for (int i = 0; i < 4; ++i) {
    float4 t4 = p[i];
    v[i * 4 + 0] = t4.x; v[i * 4 + 1] = t4.y;
    v[i * 4 + 2] = t4.z; v[i * 4 + 3] = t4.w;
  }
  float amax = 0.0f;
#pragma unroll
  for (int i = 0; i < 16; ++i) amax = fmaxf(amax, fabsf(v[i]));
  float bs8 = fp8_e4m3_rne(amax / (6.0f * gs));
  float scale = fmaxf(bs8 * gs, 1e-12f);
  unsigned short o[16];
#pragma unroll
  for (int i = 0; i < 16; ++i) {
    float q = v[i] / scale;
    float a = fminf(fabsf(q), 6.0f);
    float val = copysignf(snap_lvl(a) * bs8, q);
    o[i] = (unsigned short)(__float_as_uint(val) >> 16);
  }
  uint4 w0 = make_uint4((uint32_t)o[0] | ((uint32_t)o[1] << 16),
                        (uint32_t)o[2] | ((uint32_t)o[3] << 16),
                        (uint32_t)o[4] | ((uint32_t)o[5] << 16),
                        (uint32_t)o[6] | ((uint32_t)o[7] << 16));
  uint4 w1 = make_uint4((uint32_t)o[8]  | ((uint32_t)o[9]  << 16),
                        (uint32_t)o[10] | ((uint32_t)o[11] << 16),
                        (uint32_t)o[12] | ((uint32_t)o[13] << 16),
                        (uint32_t)o[14] | ((uint32_t)o[15] << 16));
  uint4* op = reinterpret_cast<uint4*>(out + (size_t)b * 16);
  op[0] = w0;
  op[1] = w1;
}

// ---------------- bf16 GEMM, C = A * B^T ; 256x256 tile, m201 8-phase schedule ----------------

__device__ __forceinline__ void async_lds16(const void* g, void* l) {
  __builtin_amdgcn_global_load_lds((__attribute__((address_space(1))) void*)(g),
                                   (__attribute__((address_space(3))) void*)(l),
                                   16, 0, 0);
}

#define DSR(dst, a) asm volatile("ds_read_b128 %0, %1" : "=v"(dst) : "v"(a))
#define VMC(S) asm volatile("s_waitcnt vmcnt(" S ")" ::: "memory")
#define BCB(x) __builtin_bit_cast(bf16x8, x)

#define MF4(mi, ar) do {                                                       \
    acc[mi][0] = __builtin_amdgcn_mfma_f32_16x16x32_bf16(BCB(ar), BCB(bT0), acc[mi][0], 0, 0, 0); \
    acc[mi][1] = __builtin_amdgcn_mfma_f32_16x16x32_bf16(BCB(ar), BCB(bT1), acc[mi][1], 0, 0, 0); \
    acc[mi][2] = __builtin_amdgcn_mfma_f32_16x16x32_bf16(BCB(ar), BCB(bT2), acc[mi][2], 0, 0, 0); \
    acc[mi][3] = __builtin_amdgcn_mfma_f32_16x16x32_bf16(BCB(ar), BCB(bT3), acc[mi][3], 0, 0, 0); \
  } while (0)

// stage units (1 gload_lds each); per-tile unit order: A0, B0, A1, B1
#define SG_A0(T_, SO) async_lds16(pA0 + (size_t)(T_) * BKT, (char*)As + (SO) + lo0)
#define SG_B0(T_, SO) async_lds16(pB0 + (size_t)(T_) * BKT, (char*)Bs + (SO) + lo0)
#define SG_A1(T_, SO) async_lds16(pA1 + (size_t)(T_) * BKT, (char*)As + (SO) + lo1)
#define SG_B1(T_, SO) async_lds16(pB1 + (size_t)(T_) * BKT, (char*)Bs + (SO) + lo1)

// m201 phase: {ds-reads; stage; [vmcnt]; barrier; lgkm(0); setprio1; 16 MFMA; setprio0; barrier}
#define PH_LO(SOFF, STG, VMS) do {                                             \
    DSR(bT0, adB[0] + (SOFF)); DSR(bT1, adB[1] + (SOFF));                      \
    DSR(bT2, adB[2] + (SOFF)); DSR(bT3, adB[3] + (SOFF));                      \
    DSR(aL0, adA[0] + (SOFF)); DSR(aL1, adA[1] + (SOFF));                      \
    DSR(aL2, adA[2] + (SOFF)); DSR(aL3, adA[3] + (SOFF));                      \
    STG;                                                                       \
    VMS;                                                                       \
    __builtin_amdgcn_sched_barrier(0);                                         \
    __builtin_amdgcn_s_barrier();                                              \
    asm volatile("s_waitcnt lgkmcnt(0)" ::: "memory");                         \
    __builtin_amdgcn_sched_barrier(0);                                         \
    __builtin_amdgcn_s_setprio(1);                                             \
    MF4(0, aL0); MF4(1, aL1); MF4(2, aL2); MF4(3, aL3);                        \
    __builtin_amdgcn_s_setprio(0);                                             \
    __builtin_amdgcn_sched_barrier(0);                                         \
    __builtin_amdgcn_s_barrier();                                              \
  } while (0)

#define PH_HI(SOFF, STG, VMS) do {                                             \
    DSR(aH0, adA[4] + (SOFF)); DSR(aH1, adA[5] + (SOFF));                      \
    DSR(aH2, adA[6] + (SOFF)); DSR(aH3, adA[7] + (SOFF));                      \
    STG;                                                                       \
    VMS;                                                                       \
    __builtin_amdgcn_sched_barrier(0);                                         \
    __builtin_amdgcn_s_barrier();                                              \
    asm volatile("s_waitcnt lgkmcnt(0)" ::: "memory");                         \
    __builtin_amdgcn_sched_barrier(0);                                         \
    __builtin_amdgcn_s_setprio(1);                                             \
    MF4(4, aH0); MF4(5, aH1); MF4(6, aH2); MF4(7, aH3);                        \
    __builtin_amdgcn_s_setprio(0);                                             \
    __builtin_amdgcn_sched_barrier(0);                                         \
    __builtin_amdgcn_s_barrier();                                              \
  } while (0)

__global__ __launch_bounds__(512, 2) void gemm_bt_bf16(
    const unsigned short* __restrict__ A, const unsigned short* __restrict__ B,
    const float* __restrict__ bias, const float* __restrict__ gsx,
    const float* __restrict__ gsw, float* __restrict__ C,
    int M, int N, int K) {
  __shared__ __align__(16) unsigned short As[4 * 8192];   // 64 KiB
  __shared__ __align__(16) unsigned short Bs[4 * 8192];   // 64 KiB

  const int t = threadIdx.x;
  const int l = t & 63;
  const int w = t >> 6;
  const int wm = w >> 2, wn = w & 3;     // 2x4 waves; wave tile = 128(M) x 64(N)

  // bijective XCD swizzle (nwg = 512, divisible by 8)
  const int nbn = N / BN;
  const int nwg = (M / BM) * nbn;
  const int cpx = nwg >> 3;
  int bid = blockIdx.x;
  int logical = (bid & 7) * cpx + (bid >> 3);
  const int bm = logical / nbn, bn = logical % nbn;
  const int brow = bm * BM, bcol = bn * BN;

  // staging: linear LDS dest, inverse-swizzled global source (involution q^(((q>>7)&3)<<4))
  unsigned int b0 = (unsigned int)t * 16u;
  unsigned int b1 = b0 + 8192u;
  unsigned int bp0 = b0 ^ (((b0 >> 7) & 3u) << 4);
  unsigned int bp1 = b1 ^ (((b1 >> 7) & 3u) << 4);
  const unsigned int lo0 = b0, lo1 = b1;
  const unsigned short* pA0 = A + (size_t)(brow + (bp0 >> 6)) * K + ((bp0 & 63u) >> 1);
  const unsigned short* pA1 = A + (size_t)(brow + (bp1 >> 6)) * K + ((bp1 & 63u) >> 1);
  const unsigned short* pB0 = B + (size_t)(bcol + (bp0 >> 6)) * K + ((bp0 & 63u) >> 1);
  const unsigned short* pB1 = B + (size_t)(bcol + (bp1 >> 6)) * K + ((bp1 & 63u) >> 1);

  // swizzled fragment read addresses (32-bit LDS offsets)
  const unsigned baseAu = (unsigned)(uintptr_t)(&As[0]);
  const unsigned baseBu = (unsigned)(uintptr_t)(&Bs[0]);
  unsigned int adA[8], adB[4];
#pragma unroll
  for (int mi = 0; mi < 8; ++mi) {
    unsigned int r = wm * 128 + mi * 16 + (l & 15);
    unsigned int q = r * 64 + ((l >> 4) << 4);
    adA[mi] = baseAu + (q ^ (((q >> 7) & 3u) << 4));
  }
#pragma unroll
  for (int ni = 0; ni < 4; ++ni) {
    unsigned int r = wn * 64 + ni * 16 + (l & 15);
    unsigned int q = r * 64 + ((l >> 4) << 4);
    adB[ni] = baseBu + (q ^ (((q >> 7) & 3u) << 4));
  }

  f32x4 acc[8][4] = {};
  u32x4 aL0, aL1, aL2, aL3, aH0, aH1, aH2, aH3, bT0, bT1, bT2, bT3;

  // prologue: stage tiles 0,1,2 (unit order A0,B0,A1,B1); confirm tile 0
  SG_A0(0, 0);        SG_B0(0, 0);        SG_A1(0, 0);        SG_B1(0, 0);
  SG_A0(1, SLOT);     SG_B0(1, SLOT);     SG_A1(1, SLOT);     SG_B1(1, SLOT);
  SG_A0(2, 2 * SLOT); SG_B0(2, 2 * SLOT); SG_A1(2, 2 * SLOT); SG_B1(2, 2 * SLOT);
  VMC("8");
  __builtin_amdgcn_s_barrier();

  // 62 uniform iters: tiles 2i,2i+1; stage X=2i+3 (ph1-2), Y=2i+4 (ph3-4)
#pragma unroll 1
  for (int i = 0; i < 62; ++i) {
    const int base = (i & 1) * 2;
    const int s0 = base * SLOT;
    const int s1 = s0 + SLOT;
    const int sX = (base ^ 3) * SLOT;
    const int sY = s0;
    const int X = 2 * i + 3, Y = 2 * i + 4;
    PH_LO(s0, { SG_A0(X, sX); SG_B0(X, sX); }, (void)0);
    PH_HI(s0, { SG_A1(X, sX); SG_B1(X, sX); }, VMC("8"));
    PH_LO(s1, { SG_A0(Y, sY); SG_B0(Y, sY); }, (void)0);
    PH_HI(s1, { SG_A1(Y, sY); SG_B1(Y, sY); }, VMC("8"));
  }
  // iter 62: tiles 124 (slot 0), 125 (slot 1); stage X=127 -> slot 3; Y skipped
  PH_LO(0, { SG_A0(127, 3 * SLOT); SG_B0(127, 3 * SLOT); }, (void)0);
  PH_HI(0, { SG_A1(127, 3 * SLOT); SG_B1(127, 3 * SLOT); }, VMC("8"));
  PH_LO(SLOT, {}, (void)0);
  PH_HI(SLOT, {}, VMC("4"));
  // iter 63: tiles 126 (slot 2), 127 (slot 3); no stages
  PH_LO(2 * SLOT, {}, VMC("0"));
  PH_HI(2 * SLOT, {}, (void)0);
  PH_LO(3 * SLOT, {}, (void)0);
  PH_HI(3 * SLOT, {}, (void)0);

  // ---- epilogue ----
  const float gscale = gsx[0] * gsw[0];
  float bias_r[4];
#pragma unroll
  for (int ni = 0; ni < 4; ++ni)
    bias_r[ni] = bias[bcol + wn * 64 + ni * 16 + (l & 15)];
#pragma unroll
  for (int mi = 0; mi < 8; ++mi) {
#pragma unroll
    for (int ni = 0; ni < 4; ++ni) {
#pragma unroll
      for (int r = 0; r < 4; ++r) {
        int row = brow + wm * 128 + mi * 16 + (l >> 4) * 4 + r;
        int col = bcol + wn * 64 + ni * 16 + (l & 15);
        C[(size_t)row * N + col] = acc[mi][ni][r] * gscale + bias_r[ni];
      }
    }
  }
}

// ---------------- launch ----------------

extern "C" void kernel_launch(void* const* d_in, const int* in_sizes, int n_in,
                              void* d_out, int out_size, void* d_ws, size_t ws_size,
                              hipStream_t stream) {
  const float* x    = (const float*)d_in[0];
  const float* wgt  = (const float*)d_in[1];
  const float* bias = (const float*)d_in[2];
  const float* isc  = (const float*)d_in[3];
  const float* wsc  = (const float*)d_in[4];
  float* out = (float*)d_out;

  const int N = in_sizes[2];            // 4096
  const int K = in_sizes[1] / N;        // 4096
  const int M = in_sizes[0] / K;        // 8192

  unsigned short* Aq = (unsigned short*)d_ws;
  unsigned short* Bq = Aq + (size_t)M * K;

  int nblkA = M * K / 16;
  quant_nvfp4<<<(nblkA + 255) / 256, 256, 0, stream>>>(x, Aq, isc, nblkA);
  int nblkB = N * K / 16;
  quant_nvfp4<<<(nblkB + 255) / 256, 256, 0, stream>>>(wgt, Bq, wsc, nblkB);

  dim3 grid((M / BM) * (N / BN));
  gemm_bt_bf16<<<grid, 512, 0, stream>>>(Aq, Bq, bias, isc, wsc, out, M, N, K);
}